// Round 9
// baseline (163.694 us; speedup 1.0000x reference)
//
#include <hip/hip_runtime.h>
#include <hip/hip_bf16.h>
#include <stdint.h>

typedef __attribute__((ext_vector_type(8))) short s16x8;
typedef __attribute__((ext_vector_type(4))) short s16x4;
typedef __attribute__((ext_vector_type(4))) float f32x4;

#define T_   2048
#define NH   16
#define HD   64
#define DIN  1024
#define SCALE_LOG2 0.18033688011112042f  // (1/8)*log2(e)

#define MFMA32(a, b, c) __builtin_amdgcn_mfma_f32_16x16x32_bf16(a, b, c, 0, 0, 0)

// RTNE fp32 -> bf16
__device__ __forceinline__ unsigned short f2bf(float f) {
  union { float f; uint32_t u; } c; c.f = f;
  uint32_t u = c.u;
  return (unsigned short)((u + 0x7FFFu + ((u >> 16) & 1u)) >> 16);
}

__device__ __forceinline__ uint32_t pk_bf16(float a, float b) {
  __hip_bfloat162 h = __float22bfloat162_rn(make_float2(a, b));
  return *reinterpret_cast<uint32_t*>(&h);
}

// async global->LDS, 16B per lane (GEMM staging)
#define GLL(gp, lp) __builtin_amdgcn_global_load_lds( \
    (__attribute__((address_space(1))) void*)(gp),    \
    (__attribute__((address_space(3))) void*)(lp), 16, 0, 0)

// ---------------- kernel 1: fp32 -> bf16 conversion ----------------
__global__ __launch_bounds__(256) void cvt_kernel(
    const float* __restrict__ x,  const float* __restrict__ wq,
    const float* __restrict__ wk, const float* __restrict__ wv,
    unsigned short* __restrict__ xb, unsigned short* __restrict__ wb) {
  int i = (blockIdx.x * 256 + threadIdx.x) * 4;
  float4 v;
  unsigned short* dp;
  if (i < 4194304) {
    v = *(const float4*)(x + i);
    dp = xb + i;
  } else {
    int j = i - 4194304;
    int seg = j >> 20, r = j & 1048575;
    const float* w = (seg == 0) ? wq : (seg == 1) ? wk : wv;
    v = *(const float4*)(w + r);
    dp = wb + j;
  }
  ushort4 o;
  o.x = f2bf(v.x); o.y = f2bf(v.y); o.z = f2bf(v.z); o.w = f2bf(v.w);
  *(ushort4*)dp = o;
}

// ---------------- kernel 2: QKV projection GEMM (round-7, unchanged) -------
__global__ __launch_bounds__(256) void qkv_gemm(
    const unsigned short* __restrict__ A, const unsigned short* __restrict__ Bm,
    unsigned short* __restrict__ qkv) {
  __shared__ __attribute__((aligned(16))) unsigned short Alds[128 * 64];
  __shared__ __attribute__((aligned(16))) unsigned short Blds[128 * 64];
  const int tid = threadIdx.x;
  const int lane = tid & 63, wave = tid >> 6;
  const int wm = wave >> 1, wn = wave & 1;
  const int m0 = blockIdx.y * 128, n0 = blockIdx.x * 128;

  f32x4 acc[4][4] = {};

  const int srow = wave * 32 + (lane >> 3);
  const int scol = (((lane & 7) ^ ((lane >> 3) & 7))) * 8;
  const unsigned short* ag = A  + (size_t)(m0 + srow) * DIN + scol;
  const unsigned short* bg = Bm + (size_t)(n0 + srow) * DIN + scol;
  unsigned short* al = &Alds[wave * 32 * 64];
  unsigned short* bl = &Blds[wave * 32 * 64];

  const int l16 = lane & 15, quad = lane >> 4;
  const int sw = l16 & 7;

  for (int k0 = 0; k0 < DIN; k0 += 64) {
    __syncthreads();
#pragma unroll
    for (int i = 0; i < 4; i++) {
      GLL(ag + (size_t)i * 8 * DIN + k0, al + i * 512);
      GLL(bg + (size_t)i * 8 * DIN + k0, bl + i * 512);
    }
    __syncthreads();
#pragma unroll
    for (int ks = 0; ks < 2; ks++) {
      const int cl = ((ks * 4 + quad) ^ sw) * 8;
      s16x8 af[4], bf[4];
#pragma unroll
      for (int mt = 0; mt < 4; mt++)
        af[mt] = *(const s16x8*)&Alds[(wm * 64 + mt * 16 + l16) * 64 + cl];
#pragma unroll
      for (int nt = 0; nt < 4; nt++)
        bf[nt] = *(const s16x8*)&Blds[(wn * 64 + nt * 16 + l16) * 64 + cl];
#pragma unroll
      for (int mt = 0; mt < 4; mt++)
#pragma unroll
        for (int nt = 0; nt < 4; nt++)
          acc[mt][nt] = MFMA32(af[mt], bf[nt], acc[mt][nt]);
    }
  }

#pragma unroll
  for (int mt = 0; mt < 4; mt++) {
    int mbase = m0 + wm * 64 + mt * 16 + (quad << 2);
    int b = mbase >> 11, t = mbase & 2047;
#pragma unroll
    for (int nt = 0; nt < 4; nt++) {
      int n = n0 + wn * 64 + nt * 16 + l16;
      int sel = n >> 10, h = (n >> 6) & 15, d = n & 63;
      int bh = b * NH + h;
      if (sel == 2) {
        ushort4 pk;
        pk.x = f2bf(acc[mt][nt][0]); pk.y = f2bf(acc[mt][nt][1]);
        pk.z = f2bf(acc[mt][nt][2]); pk.w = f2bf(acc[mt][nt][3]);
        *(ushort4*)&qkv[8388608 + (size_t)(bh * HD + d) * T_ + t] = pk;
      } else {
        float qs = (sel == 0) ? SCALE_LOG2 : 1.f;
#pragma unroll
        for (int r = 0; r < 4; r++)
          qkv[(size_t)sel * 4194304 + (size_t)(bh * T_ + t + r) * HD + d] =
              f2bf(acc[mt][nt][r] * qs);
      }
    }
  }
}

// ---------------- kernel 3: causal flash attention (key-split waves) -------
// 64-q blocks. Wave w owns key-slice [16w,16w+16) of every K-tile, all 64 q.
// S^T = K_slice·Q^T (A=K direct-global regs, B=Q regs). Its C-layout
// (row=key=quad*4+r, col=q=l16) doubles as the PV A-layout under the
// virtual-key mapping k'=quad*8+r (upper half zero) -> P never touches LDS.
// PV/l-sums emulate K=16 MFMA via zero-padded 16x16x32. V staged in swizzled
// LDS; per-wave V-frag = b64 read. End: 2-round all-to-all O reduction + l
// table through LDS (compile-time register indexing only).
__global__ __launch_bounds__(256) void attn_kernel(
    const unsigned short* __restrict__ qkv, float* __restrict__ out) {
  __shared__ __attribute__((aligned(16))) unsigned char smem[28672];
  unsigned short* Vt = (unsigned short*)smem;      // 64x64 shorts, swizzled
  float* Red = (float*)smem;                       // 12 regions x 512 floats
  float* Lred = (float*)(smem + 24576);            // [4][64] floats

  const int lane = threadIdx.x & 63, wave = threadIdx.x >> 6;
  const int l16 = lane & 15, quad = lane >> 4;
  const int qt = 31 - blockIdx.y, bh = blockIdx.x;
  const int q0 = qt * 64;
  const size_t bh_off = (size_t)bh * (T_ * HD);
  const unsigned short* Q  = qkv + bh_off;            // [t][d], pre-scaled
  const unsigned short* Kb = qkv + 4194304 + bh_off;  // [t][d]
  const unsigned short* Vb = qkv + 8388608 + bh_off;  // [d][t]

  // Q frags: B-operand (n=q) for all 4 q-subtiles
  s16x8 qf[4][2];
#pragma unroll
  for (int nq = 0; nq < 4; nq++) {
    const unsigned short* qp = Q + (size_t)(q0 + nq * 16 + l16) * HD + quad * 8;
    qf[nq][0] = *(const s16x8*)(qp);
    qf[nq][1] = *(const s16x8*)(qp + 32);
  }

  const int sr = threadIdx.x >> 3;        // V staging row (d) 0..31
  const int sc = (threadIdx.x & 7) * 8;   // linear chunk
  const int swc = (((threadIdx.x & 7) ^ (sr & 7))) * 8;  // swizzled chunk

  // prefetch V tile 0 + K slice 0
  s16x8 vr0 = *(const s16x8*)&Vb[(size_t)sr * T_ + sc];
  s16x8 vr1 = *(const s16x8*)&Vb[(size_t)(sr + 32) * T_ + sc];
  const unsigned short* kp0 = Kb + (size_t)(wave * 16 + l16) * HD + quad * 8;
  s16x8 kf0 = *(const s16x8*)(kp0);
  s16x8 kf1 = *(const s16x8*)(kp0 + 32);

  const s16x8 ones8 = {0x3F80, 0x3F80, 0x3F80, 0x3F80,
                       0x3F80, 0x3F80, 0x3F80, 0x3F80};
  f32x4 o[4][4] = {};   // [mq][nd] partial O over this wave's key-slice
  f32x4 lacc[4] = {};   // [mq] partial row-sums (replicated across l16)

  // V-frag b64 offset: logical t-chunk (2w + quad>>1), phys ^= (d&7)=l16&7
  const int vchunk = (((2 * wave + (quad >> 1)) ^ (l16 & 7)) << 3) + (quad & 1) * 4;

  for (int kt = 0; kt <= qt; kt++) {
    __syncthreads();
    *(s16x8*)&Vt[sr * 64 + swc] = vr0;
    *(s16x8*)&Vt[(sr + 32) * 64 + swc] = vr1;
    if (kt < qt) {
      const unsigned short* vp = Vb + (kt + 1) * 64;
      vr0 = *(const s16x8*)&vp[(size_t)sr * T_ + sc];
      vr1 = *(const s16x8*)&vp[(size_t)(sr + 32) * T_ + sc];
    }
    __syncthreads();

    // S^T = K_slice @ Q^T : m=key_local(16), n=q(64)
    f32x4 s[4] = {};
#pragma unroll
    for (int nq = 0; nq < 4; nq++) {
      s[nq] = MFMA32(kf0, qf[nq][0], s[nq]);
      s[nq] = MFMA32(kf1, qf[nq][1], s[nq]);
    }
    if (kt < qt) {  // prefetch next K slice; overlaps exp2 + PV
      const unsigned short* kp =
          Kb + (size_t)((kt + 1) * 64 + wave * 16 + l16) * HD + quad * 8;
      kf0 = *(const s16x8*)(kp);
      kf1 = *(const s16x8*)(kp + 32);
    }

    // p = exp2(s) (+ causal mask on diagonal tile); pack zero-padded A-frags
    s16x8 pf[4];
    if (kt < qt) {
#pragma unroll
      for (int nq = 0; nq < 4; nq++) {
        float p0 = exp2f(s[nq][0]);
        float p1 = exp2f(s[nq][1]);
        float p2 = exp2f(s[nq][2]);
        float p3 = exp2f(s[nq][3]);
        union { s16x8 v; uint4 u; } pu;
        pu.u = make_uint4(pk_bf16(p0, p1), pk_bf16(p2, p3), 0u, 0u);
        pf[nq] = pu.v;
      }
    } else {
#pragma unroll
      for (int nq = 0; nq < 4; nq++) {
        const int lim = nq * 16 + l16 - wave * 16 - quad * 4;  // r <= lim
        float p0 = (0 <= lim) ? exp2f(s[nq][0]) : 0.f;
        float p1 = (1 <= lim) ? exp2f(s[nq][1]) : 0.f;
        float p2 = (2 <= lim) ? exp2f(s[nq][2]) : 0.f;
        float p3 = (3 <= lim) ? exp2f(s[nq][3]) : 0.f;
        union { s16x8 v; uint4 u; } pu;
        pu.u = make_uint4(pk_bf16(p0, p1), pk_bf16(p2, p3), 0u, 0u);
        pf[nq] = pu.v;
      }
    }

    // l += P @ 1 ; O += P @ V  (virtual key k'=quad*8+r; upper half zero)
#pragma unroll
    for (int mq = 0; mq < 4; mq++)
      lacc[mq] = MFMA32(pf[mq], ones8, lacc[mq]);
#pragma unroll
    for (int nd = 0; nd < 4; nd++) {
      s16x4 vf4 = *(const s16x4*)&Vt[(nd * 16 + l16) * 64 + vchunk];
      s16x8 vf = {vf4[0], vf4[1], vf4[2], vf4[3], 0, 0, 0, 0};
#pragma unroll
      for (int mq = 0; mq < 4; mq++)
        o[mq][nd] = MFMA32(pf[mq], vf, o[mq][nd]);
    }
  }

  // ---- cross-wave reduction ----
  __syncthreads();  // all Vt reads done; smem becomes Red/Lred
  if (l16 == 0) {   // lacc replicated across l16: one writer per quad-row
#pragma unroll
    for (int mq = 0; mq < 4; mq++)
      *(f32x4*)&Lred[wave * 64 + mq * 16 + quad * 4] = lacc[mq];
  }

  f32x4 osum[4];
#pragma unroll
  for (int nd = 0; nd < 4; nd++)
    if (nd == wave) {  // wave-uniform; compile-time register index
#pragma unroll
      for (int mq = 0; mq < 4; mq++) osum[mq] = o[mq][nd];
    }

  // two rounds: mq-pair {0,1} then {2,3}; 12 regions of 512 floats
#pragma unroll
  for (int half = 0; half < 2; half++) {
    const int mqA = half * 2, mqB = half * 2 + 1;
#pragma unroll
    for (int nd = 0; nd < 4; nd++) {
      if (nd != wave) {
        const int reg = nd * 3 + (wave > nd ? wave - 1 : wave);
        float* wr = Red + reg * 512 + lane * 8;
        *(f32x4*)&wr[0] = o[mqA][nd];
        *(f32x4*)&wr[4] = o[mqB][nd];
      }
    }
    __syncthreads();
#pragma unroll
    for (int v = 0; v < 4; v++) {
      if (v != wave) {
        const int reg = wave * 3 + (v > wave ? v - 1 : v);
        const float* rd = Red + reg * 512 + lane * 8;
        osum[mqA] += *(const f32x4*)&rd[0];
        osum[mqB] += *(const f32x4*)&rd[4];
      }
    }
    __syncthreads();
  }

  // finalize: wave w stores d-slice [16w,16w+16), all q; normalize by total l
#pragma unroll
  for (int mq = 0; mq < 4; mq++) {
    f32x4 lt = {};
#pragma unroll
    for (int v = 0; v < 4; v++)
      lt += *(const f32x4*)&Lred[v * 64 + mq * 16 + quad * 4];
    float4 res;
    res.x = osum[mq][0] / lt[0];
    res.y = osum[mq][1] / lt[1];
    res.z = osum[mq][2] / lt[2];
    res.w = osum[mq][3] / lt[3];
    *(float4*)(out + (size_t)bh * (HD * T_) + (size_t)(wave * 16 + l16) * T_ +
               q0 + mq * 16 + quad * 4) = res;
  }
}

extern "C" void kernel_launch(void* const* d_in, const int* in_sizes, int n_in,
                              void* d_out, int out_size, void* d_ws, size_t ws_size,
                              hipStream_t stream) {
  const float* x  = (const float*)d_in[0];
  const float* wq = (const float*)d_in[1];
  const float* wk = (const float*)d_in[2];
  const float* wv = (const float*)d_in[3];
  float* out = (float*)d_out;

  unsigned short* xb  = (unsigned short*)d_ws;       // 4194304 bf16
  unsigned short* wb  = xb + 4194304;                // 3145728 bf16 [Wq;Wk;Wv]
  unsigned short* qkv = wb + 3145728;                // 3 * 4194304 bf16

  cvt_kernel<<<7168, 256, 0, stream>>>(x, wq, wk, wv, xb, wb);
  dim3 g1(24, 32);  // N/128 x M/128
  qkv_gemm<<<g1, 256, 0, stream>>>(xb, wb, qkv);
  dim3 g2(32, 32);  // bh x qt-rev (qt descending for load balance)
  attn_kernel<<<g2, 256, 0, stream>>>(qkv, out);
}